// Round 8
// baseline (186.652 us; speedup 1.0000x reference)
//
#include <hip/hip_runtime.h>
#include <hip/hip_bf16.h>
#include <stdint.h>

// Problem constants
#define B_    64
#define T_    200
#define CIN_  80
#define C_    1024
#define M_    (B_ * T_)   // 12800
#define BCEL  (B_ * C_)   // 65536

typedef __attribute__((ext_vector_type(4))) float f32x4;
typedef __attribute__((ext_vector_type(8))) _Float16 f16x8;   // 8 f16 in 4 VGPRs
typedef __attribute__((ext_vector_type(4))) unsigned int u32x4;

// ---------------------------------------------------------------------------
// FUSED pointwise-conv + depthwise(K=7) + BN1 + LIF1.
// One thread per (b,o). All 256 threads of a block share b, so x rows are
// block-uniform: staged in double-buffered LDS (8 t-rows = 2.56 KB/buf).
// Each thread holds its pw_w row (80 VGPRs — free: grid fixes 1 wave/SIMD).
// Arithmetic per output is BIT-IDENTICAL to the validated split kernels:
//   acc: strict ascending-k fmaf chain; pt = acc + pw_b;
//   u = dw_b + sum(dw[k]*ring[k]) ascending; u = fmaf(u,inv,add);
//   v = fmaf(0.5,v,u); spike; hard reset.
// Output: spike f16 bits (0x3C00/0) in s1:[T,B,C].
// ---------------------------------------------------------------------------
#define CHT 8    // t-rows per LDS chunk (25 chunks exactly)

__global__ __launch_bounds__(256) void fused_pw_dw_lif(
    const float* __restrict__ x, const float* __restrict__ pw_w,
    const float* __restrict__ pw_b, const float* __restrict__ dw_w,
    const float* __restrict__ dw_b, const float* __restrict__ gam,
    const float* __restrict__ bet, const float* __restrict__ mu,
    const float* __restrict__ var, ushort* __restrict__ s1) {
  __shared__ __align__(16) float xs[2][CHT * CIN_];   // 2 x 2.56 KB

  const int tid = threadIdx.x;
  const int b = blockIdx.x >> 2;                 // uniform per block
  const int o = ((blockIdx.x & 3) << 8) | tid;

  // per-thread pointwise weight row (80 VGPRs)
  float w[CIN_];
#pragma unroll
  for (int k = 0; k < CIN_; k += 4) {
    float4 q = *(const float4*)(pw_w + (size_t)o * CIN_ + k);
    w[k] = q.x; w[k + 1] = q.y; w[k + 2] = q.z; w[k + 3] = q.w;
  }
  const float pb = pw_b[o];
  const float d0 = dw_w[o * 7 + 0], d1 = dw_w[o * 7 + 1], d2 = dw_w[o * 7 + 2],
              d3 = dw_w[o * 7 + 3], d4 = dw_w[o * 7 + 4], d5 = dw_w[o * 7 + 5],
              d6 = dw_w[o * 7 + 6];
  const float db = dw_b[o];
  const float inv = (float)((double)gam[o] / sqrt((double)var[o] + 1e-5));
  const float add = (float)((double)bet[o] - (double)mu[o] * (double)inv);

  const float* xb_ = x + (size_t)b * T_ * CIN_;

  // stage chunk 0 (640 floats, coalesced)
  {
    float v0 = xb_[tid];
    float v1 = xb_[tid + 256];
    xs[0][tid] = v0;
    xs[0][tid + 256] = v1;
    if (tid < 128) xs[0][tid + 512] = xb_[tid + 512];
  }
  __syncthreads();

  float r0 = 0.f, r1 = 0.f, r2 = 0.f, r3 = 0.f, r4 = 0.f, r5 = 0.f, r6 = 0.f;
  float v = 0.f;
  const size_t obase = (size_t)b * C_ + o;

#define EMIT_STEP(PT, TIDX)                                                    \
  do {                                                                         \
    r0 = r1; r1 = r2; r2 = r3; r3 = r4; r4 = r5; r5 = r6; r6 = (PT);           \
    int t_ = (TIDX);                                                           \
    if (t_ >= 0) {                                                             \
      float u = db;                                                            \
      u = fmaf(d0, r0, u); u = fmaf(d1, r1, u); u = fmaf(d2, r2, u);           \
      u = fmaf(d3, r3, u); u = fmaf(d4, r4, u); u = fmaf(d5, r5, u);           \
      u = fmaf(d6, r6, u);                                                     \
      u = fmaf(u, inv, add);                                                   \
      v = fmaf(0.5f, v, u);                                                    \
      bool sp = (v - 1.0f) >= 0.0f;                                            \
      s1[obase + (size_t)t_ * BCEL] = sp ? (ushort)0x3C00 : (ushort)0;         \
      v = sp ? 0.0f : v;                                                       \
    }                                                                          \
  } while (0)

  for (int c = 0; c < T_ / CHT; ++c) {
    // register-prefetch next chunk (overlaps this chunk's compute)
    float p0 = 0.f, p1 = 0.f, p2 = 0.f;
    if (c + 1 < T_ / CHT) {
      const float* src = xb_ + (size_t)(c + 1) * (CHT * CIN_);
      p0 = src[tid];
      p1 = src[tid + 256];
      if (tid < 128) p2 = src[tid + 512];
    }
    const float* rowb = &xs[c & 1][0];
#pragma unroll
    for (int s = 0; s < CHT; ++s) {
      float acc = 0.f;
#pragma unroll
      for (int k4 = 0; k4 < CIN_ / 4; ++k4) {
        float4 q = *(const float4*)(rowb + s * CIN_ + k4 * 4);   // broadcast
        acc = fmaf(q.x, w[k4 * 4 + 0], acc);
        acc = fmaf(q.y, w[k4 * 4 + 1], acc);
        acc = fmaf(q.z, w[k4 * 4 + 2], acc);
        acc = fmaf(q.w, w[k4 * 4 + 3], acc);
      }
      float pt = acc + pb;
      EMIT_STEP(pt, c * CHT + s - 3);
    }
    __syncthreads();   // all waves done reading buf[c&1]'s sibling use
    if (c + 1 < T_ / CHT) {
      xs[(c + 1) & 1][tid] = p0;
      xs[(c + 1) & 1][tid + 256] = p1;
      if (tid < 128) xs[(c + 1) & 1][tid + 512] = p2;
    }
    __syncthreads();
  }
  // tail: 3 zero-pad steps emit t = 197,198,199
  EMIT_STEP(0.f, 197);
  EMIT_STEP(0.f, 198);
  EMIT_STEP(0.f, 199);
#undef EMIT_STEP
}

// ---------------------------------------------------------------------------
// Scaled 2-way f16 split of the linear weights: w ~= w0 + 2^-11 w1s.
// Exact when multiplied by {0,1} spikes (products exact, f32 accum).
// ---------------------------------------------------------------------------
__global__ __launch_bounds__(256) void split_w(
    const float* __restrict__ w, ushort* __restrict__ w0,
    ushort* __restrict__ w1, int n) {
  int i = blockIdx.x * 256 + threadIdx.x;
  if (i >= n) return;
  float x = w[i];
  union { _Float16 h; ushort u; } h0, h1;
  h0.h = (_Float16)x;
  if (fabsf(x) < 6.1035156e-5f) h0.u = 0;   // keep w0 out of f16 subnormals
  float r = x - (float)h0.h;
  h1.h = (_Float16)(r * 2048.0f);
  w0[i] = h0.u;
  w1[i] = h1.u;
}

// ---------------------------------------------------------------------------
// MFMA f16 GEMM, 2-term weight split, single accumulator:
//   y = S*w0^T + (S&0x1000)*w1s^T
// 128x128 tile, BK=32, 4 waves, double-buffered LDS (2x24KB), one barrier
// per K-step: stage(next) overlaps MFMA(cur). LDS XOR-swizzle (rule #21),
// proven 0 bank conflicts in round 6.  [VERBATIM round-6 kernel, 76 us]
// ---------------------------------------------------------------------------
#define BM 128
#define BN 128
#define BKg 32

__global__ __launch_bounds__(256) void gemm_mfma2p(
    const ushort* __restrict__ A,
    const ushort* __restrict__ B0,
    const ushort* __restrict__ B1,
    float* __restrict__ Cout) {
  const int K = C_;
  const int N = C_;
  // [buf][mat: 0=A,1=B0,2=B1][row*32 + col]
  __shared__ __align__(16) ushort lds[2][3][BM * BKg];   // 48 KB

  const int tid  = threadIdx.x;
  const int lane = tid & 63;
  const int wm = ((tid >> 6) >> 1) * 64;
  const int wn = ((tid >> 6) & 1) * 64;

  // XCD-aware swizzle: 800 blocks -> 100 contiguous per XCD, n fastest
  int lin = blockIdx.x;
  int qq = gridDim.x >> 3;                 // 100
  int wg = (lin & 7) * qq + (lin >> 3);
  const int m0 = (wg >> 3) * BM;
  const int n0 = (wg & 7) * BN;

  const int r0 = tid >> 2, r1 = r0 + 64;
  const int kc = (tid & 3) * 8;
  const int ks = kc ^ (((tid >> 3) & 3) << 3);

  const int fr = lane & 15;
  const int k8 = (lane >> 4) * 8;
  const int k8s = k8 ^ (((fr >> 1) & 3) << 3);

  f32x4 acc[4][4] = {};

#define STAGE(bufi, kk0)                                                       \
  do {                                                                         \
    __builtin_amdgcn_global_load_lds(                                          \
        (const __attribute__((address_space(1))) uint32_t*)(A + (size_t)(m0 + r0) * K + (kk0) + ks),  \
        (__attribute__((address_space(3))) uint32_t*)&lds[bufi][0][tid * 8], 16, 0, 0);               \
    __builtin_amdgcn_global_load_lds(                                          \
        (const __attribute__((address_space(1))) uint32_t*)(A + (size_t)(m0 + r1) * K + (kk0) + ks),  \
        (__attribute__((address_space(3))) uint32_t*)&lds[bufi][0][(tid + 256) * 8], 16, 0, 0);       \
    __builtin_amdgcn_global_load_lds(                                          \
        (const __attribute__((address_space(1))) uint32_t*)(B0 + (size_t)(n0 + r0) * K + (kk0) + ks), \
        (__attribute__((address_space(3))) uint32_t*)&lds[bufi][1][tid * 8], 16, 0, 0);               \
    __builtin_amdgcn_global_load_lds(                                          \
        (const __attribute__((address_space(1))) uint32_t*)(B0 + (size_t)(n0 + r1) * K + (kk0) + ks), \
        (__attribute__((address_space(3))) uint32_t*)&lds[bufi][1][(tid + 256) * 8], 16, 0, 0);       \
    __builtin_amdgcn_global_load_lds(                                          \
        (const __attribute__((address_space(1))) uint32_t*)(B1 + (size_t)(n0 + r0) * K + (kk0) + ks), \
        (__attribute__((address_space(3))) uint32_t*)&lds[bufi][2][tid * 8], 16, 0, 0);               \
    __builtin_amdgcn_global_load_lds(                                          \
        (const __attribute__((address_space(1))) uint32_t*)(B1 + (size_t)(n0 + r1) * K + (kk0) + ks), \
        (__attribute__((address_space(3))) uint32_t*)&lds[bufi][2][(tid + 256) * 8], 16, 0, 0);       \
  } while (0)

  STAGE(0, 0);
  __syncthreads();

  int buf = 0;
  for (int k0 = 0; k0 < K; k0 += BKg) {
    union HU { f16x8 h; u32x4 u; };
    f16x8 af[4], a2f[4], b0f[4], b1f[4];
#pragma unroll
    for (int m = 0; m < 4; ++m) {
      HU t;
      t.h = *(const f16x8*)&lds[buf][0][(wm + m * 16 + fr) * BKg + k8s];
      af[m] = t.h;
      t.u &= 0x10001000u;      // {0,1.0f16} -> {0, 2^-11} exactly
      a2f[m] = t.h;
    }
#pragma unroll
    for (int n = 0; n < 4; ++n) {
      b0f[n] = *(const f16x8*)&lds[buf][1][(wn + n * 16 + fr) * BKg + k8s];
      b1f[n] = *(const f16x8*)&lds[buf][2][(wn + n * 16 + fr) * BKg + k8s];
    }
    if (k0 + BKg < K) STAGE(buf ^ 1, k0 + BKg);
#pragma unroll
    for (int m = 0; m < 4; ++m)
#pragma unroll
      for (int n = 0; n < 4; ++n) {
        acc[m][n] = __builtin_amdgcn_mfma_f32_16x16x32_f16(
            af[m], b0f[n], acc[m][n], 0, 0, 0);
        acc[m][n] = __builtin_amdgcn_mfma_f32_16x16x32_f16(
            a2f[m], b1f[n], acc[m][n], 0, 0, 0);
      }
    __syncthreads();
    buf ^= 1;
  }
#undef STAGE

  const int ccol = lane & 15;
  const int crow = (lane >> 4) * 4;
#pragma unroll
  for (int m = 0; m < 4; ++m)
#pragma unroll
    for (int n = 0; n < 4; ++n)
#pragma unroll
      for (int j = 0; j < 4; ++j) {
        int row = m0 + wm + m * 16 + crow + j;
        int col = n0 + wn + n * 16 + ccol;
        Cout[(size_t)row * N + col] = acc[m][n][j];
      }
}

// ---------------------------------------------------------------------------
// BN2 + LIF2 + residual, chunked T by 8 with next-chunk prefetch.
// Safe when y == out (owner-thread read-before-write per element).
// ---------------------------------------------------------------------------
__global__ __launch_bounds__(256) void bn_lif_add(
    const float* __restrict__ y, const ushort* __restrict__ s1b,
    const float* __restrict__ gam, const float* __restrict__ bet,
    const float* __restrict__ mu, const float* __restrict__ var,
    float* __restrict__ out) {
  int gid = blockIdx.x * blockDim.x + threadIdx.x;
  int o = gid & 1023;

  float inv = (float)((double)gam[o] / sqrt((double)var[o] + 1e-5));
  float add = (float)((double)bet[o] - (double)mu[o] * (double)inv);

  float v = 0.f;
  size_t base = (size_t)gid;
  float yv[8]; ushort sv[8];
#pragma unroll
  for (int j = 0; j < 8; ++j) {
    yv[j] = y[base + (size_t)j * BCEL];
    sv[j] = s1b[base + (size_t)j * BCEL];
  }
  for (int c = 0; c < T_ / 8; ++c) {
    int t0 = c * 8;
    float yn[8] = {0,0,0,0,0,0,0,0}; ushort sn[8] = {0,0,0,0,0,0,0,0};
    if (c + 1 < T_ / 8) {
#pragma unroll
      for (int j = 0; j < 8; ++j) {
        size_t idx = base + (size_t)(t0 + 8 + j) * BCEL;
        yn[j] = y[idx];
        sn[j] = s1b[idx];
      }
    }
#pragma unroll
    for (int j = 0; j < 8; ++j) {
      float u = fmaf(yv[j], inv, add);
      v = fmaf(0.5f, v, u);
      bool sp = (v - 1.0f) >= 0.0f;
      float s1v = sv[j] ? 1.0f : 0.0f;
      out[base + (size_t)(t0 + j) * BCEL] = (sp ? 1.0f : 0.0f) + s1v;
      v = sp ? 0.0f : v;
    }
#pragma unroll
    for (int j = 0; j < 8; ++j) { yv[j] = yn[j]; sv[j] = sn[j]; }
  }
}

// ---------------------------------------------------------------------------
extern "C" void kernel_launch(void* const* d_in, const int* in_sizes, int n_in,
                              void* d_out, int out_size, void* d_ws,
                              size_t ws_size, hipStream_t stream) {
  const float* x     = (const float*)d_in[0];
  const float* pw_w  = (const float*)d_in[1];
  const float* pw_b  = (const float*)d_in[2];
  const float* dw_w  = (const float*)d_in[3];
  const float* dw_b  = (const float*)d_in[4];
  const float* bn1g  = (const float*)d_in[5];
  const float* bn1b  = (const float*)d_in[6];
  const float* bn1m  = (const float*)d_in[7];
  const float* bn1v  = (const float*)d_in[8];
  const float* lin_w = (const float*)d_in[9];
  const float* bn2g  = (const float*)d_in[10];
  const float* bn2b  = (const float*)d_in[11];
  const float* bn2m  = (const float*)d_in[12];
  const float* bn2v  = (const float*)d_in[13];

  char* wsb  = (char*)d_ws;
  char* outb = (char*)d_out;
  const size_t PB  = (size_t)M_ * C_ * 4;        // 52,428,800  (y, f32)
  const size_t SBB = (size_t)M_ * C_ * 2;        // 26,214,400  (spikes, f16)

  const bool primary = ws_size >= PB + SBB;
  // primary : spikes @ ws+PB, lin-weights @ d_out[0:4MB), y @ ws[0:PB)
  // fallback: spikes @ d_out, memcpy -> ws[0:SBB), weights @ ws+SBB, y @ d_out
  ushort* spikes = primary ? (ushort*)(wsb + PB) : (ushort*)d_out;
  ushort* w0  = primary ? (ushort*)outb : (ushort*)(wsb + SBB);
  ushort* w1s = w0 + (size_t)C_ * C_;
  ushort* Sgemm = primary ? spikes : (ushort*)d_ws;
  float* ybuf = primary ? (float*)d_ws : (float*)d_out;

  // 1) FUSED pointwise + depthwise + BN1 + LIF1 -> f16 spike bits [T,B,C]
  fused_pw_dw_lif<<<BCEL / 256, 256, 0, stream>>>(
      x, pw_w, pw_b, dw_w, dw_b, bn1g, bn1b, bn1m, bn1v, spikes);

  // 2) fallback only: move spikes out of d_out before GEMM overwrites it
  if (!primary)
    hipMemcpyAsync(d_ws, d_out, SBB, hipMemcpyDeviceToDevice, stream);

  // 3) linear weight split
  split_w<<<(C_ * C_ + 255) / 256, 256, 0, stream>>>(lin_w, w0, w1s, C_ * C_);

  // 4) linear MFMA GEMM (r6 pipelined+swizzled): y = S.(w0 + 2^-11 w1s)^T
  gemm_mfma2p<<<(M_ / BM) * (C_ / BN), 256, 0, stream>>>(Sgemm, w0, w1s, ybuf);

  // 5) BN2 + LIF2 + residual -> d_out
  bn_lif_add<<<BCEL / 256, 256, 0, stream>>>(ybuf, Sgemm, bn2g, bn2b, bn2m,
                                             bn2v, (float*)d_out);
}

// Round 9
// 153.772 us; speedup vs baseline: 1.2138x; 1.2138x over previous
//
#include <hip/hip_runtime.h>
#include <hip/hip_bf16.h>
#include <stdint.h>

// Problem constants
#define B_    64
#define T_    200
#define CIN_  80
#define C_    1024
#define M_    (B_ * T_)   // 12800
#define BCEL  (B_ * C_)   // 65536

typedef __attribute__((ext_vector_type(4))) float f32x4;
typedef __attribute__((ext_vector_type(8))) _Float16 f16x8;   // 8 f16 in 4 VGPRs
typedef __attribute__((ext_vector_type(4))) unsigned int u32x4;

// ---------------------------------------------------------------------------
// f32 GEMM (vector ALU) for the pointwise conv: C[M,N] = A[M,K]*B[N,K]^T + bias
// 128x128 tile, 8x8 per thread as two 4-wide halves (cols tx*4 / tx*4+64,
// rows ty*4 / ty*4+64) -> 1.0 B LDS per FMA (was 2.0: the r6 64-tile was
// LDS-BW-bound at ~27us). Per-output FMA chain remains STRICT ASCENDING-K —
// bit-identical to the validated rounds-1..6 arithmetic.
// ---------------------------------------------------------------------------
__global__ __launch_bounds__(256) void gemm_abt128(
    const float* __restrict__ A, const float* __restrict__ Bm,
    const float* __restrict__ bias, float* __restrict__ C,
    int M, int N, int K) {
  __shared__ float As[16][128];   // 8 KB, k-major
  __shared__ float Bs[16][128];   // 8 KB
  const int tid = threadIdx.x;
  const int tx = tid & 15;        // col group (4 cols + 4 cols at +64)
  const int ty = tid >> 4;        // row group (4 rows + 4 rows at +64)
  const int m0 = blockIdx.x * 128;
  const int n0 = blockIdx.y * 128;
  const int lr = tid >> 1;        // 0..127 staged row
  const int lc = (tid & 1) * 8;   // 0 or 8 k-offset

  float acc[8][8] = {};           // [i: row-half*4+r][j: col-half*4+c]

  const float* Ar = A + (size_t)(m0 + lr) * K + lc;
  const float* Br = Bm + (size_t)(n0 + lr) * K + lc;

  // prefetch k0 = 0
  float4 a0 = *(const float4*)(Ar + 0);
  float4 a1 = *(const float4*)(Ar + 4);
  float4 b0 = *(const float4*)(Br + 0);
  float4 b1 = *(const float4*)(Br + 4);

  for (int k0 = 0; k0 < K; k0 += 16) {
    __syncthreads();
    As[lc + 0][lr] = a0.x; As[lc + 1][lr] = a0.y;
    As[lc + 2][lr] = a0.z; As[lc + 3][lr] = a0.w;
    As[lc + 4][lr] = a1.x; As[lc + 5][lr] = a1.y;
    As[lc + 6][lr] = a1.z; As[lc + 7][lr] = a1.w;
    Bs[lc + 0][lr] = b0.x; Bs[lc + 1][lr] = b0.y;
    Bs[lc + 2][lr] = b0.z; Bs[lc + 3][lr] = b0.w;
    Bs[lc + 4][lr] = b1.x; Bs[lc + 5][lr] = b1.y;
    Bs[lc + 6][lr] = b1.z; Bs[lc + 7][lr] = b1.w;
    __syncthreads();
    if (k0 + 16 < K) {            // prefetch next chunk; overlaps FMA block
      a0 = *(const float4*)(Ar + k0 + 16);
      a1 = *(const float4*)(Ar + k0 + 20);
      b0 = *(const float4*)(Br + k0 + 16);
      b1 = *(const float4*)(Br + k0 + 20);
    }
#pragma unroll
    for (int kk = 0; kk < 16; ++kk) {
      float4 av0 = *(const float4*)&As[kk][ty * 4];        // broadcast in wave
      float4 av1 = *(const float4*)&As[kk][ty * 4 + 64];
      float4 bv0 = *(const float4*)&Bs[kk][tx * 4];        // 2-way (free)
      float4 bv1 = *(const float4*)&Bs[kk][tx * 4 + 64];
      float avv[8] = {av0.x, av0.y, av0.z, av0.w, av1.x, av1.y, av1.z, av1.w};
      float bvv[8] = {bv0.x, bv0.y, bv0.z, bv0.w, bv1.x, bv1.y, bv1.z, bv1.w};
#pragma unroll
      for (int i = 0; i < 8; ++i)
#pragma unroll
        for (int j = 0; j < 8; ++j)
          acc[i][j] = fmaf(avv[i], bvv[j], acc[i][j]);
    }
  }

  float bj[8] = {0.f, 0.f, 0.f, 0.f, 0.f, 0.f, 0.f, 0.f};
  if (bias) {
#pragma unroll
    for (int j = 0; j < 8; ++j)
      bj[j] = bias[n0 + tx * 4 + (j & 3) + (j >> 2) * 64];
  }
#pragma unroll
  for (int i = 0; i < 8; ++i) {
    int row = m0 + ty * 4 + (i & 3) + (i >> 2) * 64;
    float4 o0, o1;
    o0.x = acc[i][0] + bj[0]; o0.y = acc[i][1] + bj[1];
    o0.z = acc[i][2] + bj[2]; o0.w = acc[i][3] + bj[3];
    o1.x = acc[i][4] + bj[4]; o1.y = acc[i][5] + bj[5];
    o1.z = acc[i][6] + bj[6]; o1.w = acc[i][7] + bj[7];
    *(float4*)&C[(size_t)row * N + n0 + tx * 4] = o0;
    *(float4*)&C[(size_t)row * N + n0 + tx * 4 + 64] = o1;
  }
}

// ---------------------------------------------------------------------------
// Depthwise conv (K=7, same pad) + BN1 + LIF1 scan, chunked T by 8 with
// 8-deep load prefetch. p:[B,T,C] f32 -> spike f16 bits in s1:[T,B,C].
// [VERBATIM round-6 kernel]
// ---------------------------------------------------------------------------
__global__ __launch_bounds__(256) void dw_bn_lif(
    const float* __restrict__ p, const float* __restrict__ dw_w,
    const float* __restrict__ dw_b, const float* __restrict__ gam,
    const float* __restrict__ bet, const float* __restrict__ mu,
    const float* __restrict__ var, ushort* __restrict__ s1) {
  int gid = blockIdx.x * blockDim.x + threadIdx.x;
  int b = gid >> 10;
  int o = gid & 1023;

  float w[7];
#pragma unroll
  for (int k = 0; k < 7; ++k) w[k] = dw_w[o * 7 + k];
  float db = dw_b[o];
  float inv = (float)((double)gam[o] / sqrt((double)var[o] + 1e-5));
  float add = (float)((double)bet[o] - (double)mu[o] * (double)inv);

  const float* pp = p + (size_t)b * T_ * C_ + o;
  float win[14];
  win[0] = 0.f; win[1] = 0.f; win[2] = 0.f;
#pragma unroll
  for (int i = 0; i < 11; ++i) win[3 + i] = pp[(size_t)i * C_];

  float v = 0.f;
  size_t obase = (size_t)b * C_ + o;
  for (int c = 0; c < T_ / 8; ++c) {
    int t0 = c * 8;
    float nx[8];
#pragma unroll
    for (int j = 0; j < 8; ++j) {
      int tn = t0 + 11 + j;
      nx[j] = (tn < T_) ? pp[(size_t)tn * C_] : 0.f;
    }
#pragma unroll
    for (int s = 0; s < 8; ++s) {
      float u = db;
#pragma unroll
      for (int k = 0; k < 7; ++k) u = fmaf(w[k], win[s + k], u);
      u = fmaf(u, inv, add);
      v = fmaf(0.5f, v, u);
      bool sp = (v - 1.0f) >= 0.0f;
      s1[obase + (size_t)(t0 + s) * BCEL] = sp ? (ushort)0x3C00 : (ushort)0;
      v = sp ? 0.0f : v;
    }
#pragma unroll
    for (int i = 0; i < 6; ++i) win[i] = win[i + 8];
#pragma unroll
    for (int j = 0; j < 8; ++j) win[6 + j] = nx[j];
  }
}

// ---------------------------------------------------------------------------
// Scaled 2-way f16 split of the linear weights: w ~= w0 + 2^-11 w1s.
// Exact when multiplied by {0,1} spikes (products exact, f32 accum).
// ---------------------------------------------------------------------------
__global__ __launch_bounds__(256) void split_w(
    const float* __restrict__ w, ushort* __restrict__ w0,
    ushort* __restrict__ w1, int n) {
  int i = blockIdx.x * 256 + threadIdx.x;
  if (i >= n) return;
  float x = w[i];
  union { _Float16 h; ushort u; } h0, h1;
  h0.h = (_Float16)x;
  if (fabsf(x) < 6.1035156e-5f) h0.u = 0;   // keep w0 out of f16 subnormals
  float r = x - (float)h0.h;
  h1.h = (_Float16)(r * 2048.0f);
  w0[i] = h0.u;
  w1[i] = h1.u;
}

// ---------------------------------------------------------------------------
// MFMA f16 GEMM, 2-term weight split, single accumulator:
//   y = S*w0^T + (S&0x1000)*w1s^T
// 128x128 tile, BK=32, 4 waves, double-buffered LDS (2x24KB), one barrier
// per K-step: stage(next) overlaps MFMA(cur). LDS XOR-swizzle (rule #21),
// proven 0 bank conflicts in round 6.  [VERBATIM round-6 kernel, 76 us]
// ---------------------------------------------------------------------------
#define BM 128
#define BN 128
#define BKg 32

__global__ __launch_bounds__(256) void gemm_mfma2p(
    const ushort* __restrict__ A,
    const ushort* __restrict__ B0,
    const ushort* __restrict__ B1,
    float* __restrict__ Cout) {
  const int K = C_;
  const int N = C_;
  // [buf][mat: 0=A,1=B0,2=B1][row*32 + col]
  __shared__ __align__(16) ushort lds[2][3][BM * BKg];   // 48 KB

  const int tid  = threadIdx.x;
  const int lane = tid & 63;
  const int wm = ((tid >> 6) >> 1) * 64;
  const int wn = ((tid >> 6) & 1) * 64;

  // XCD-aware swizzle: 800 blocks -> 100 contiguous per XCD, n fastest
  int lin = blockIdx.x;
  int qq = gridDim.x >> 3;                 // 100
  int wg = (lin & 7) * qq + (lin >> 3);
  const int m0 = (wg >> 3) * BM;
  const int n0 = (wg & 7) * BN;

  const int r0 = tid >> 2, r1 = r0 + 64;
  const int kc = (tid & 3) * 8;
  const int ks = kc ^ (((tid >> 3) & 3) << 3);

  const int fr = lane & 15;
  const int k8 = (lane >> 4) * 8;
  const int k8s = k8 ^ (((fr >> 1) & 3) << 3);

  f32x4 acc[4][4] = {};

#define STAGE(bufi, kk0)                                                       \
  do {                                                                         \
    __builtin_amdgcn_global_load_lds(                                          \
        (const __attribute__((address_space(1))) uint32_t*)(A + (size_t)(m0 + r0) * K + (kk0) + ks),  \
        (__attribute__((address_space(3))) uint32_t*)&lds[bufi][0][tid * 8], 16, 0, 0);               \
    __builtin_amdgcn_global_load_lds(                                          \
        (const __attribute__((address_space(1))) uint32_t*)(A + (size_t)(m0 + r1) * K + (kk0) + ks),  \
        (__attribute__((address_space(3))) uint32_t*)&lds[bufi][0][(tid + 256) * 8], 16, 0, 0);       \
    __builtin_amdgcn_global_load_lds(                                          \
        (const __attribute__((address_space(1))) uint32_t*)(B0 + (size_t)(n0 + r0) * K + (kk0) + ks), \
        (__attribute__((address_space(3))) uint32_t*)&lds[bufi][1][tid * 8], 16, 0, 0);               \
    __builtin_amdgcn_global_load_lds(                                          \
        (const __attribute__((address_space(1))) uint32_t*)(B0 + (size_t)(n0 + r1) * K + (kk0) + ks), \
        (__attribute__((address_space(3))) uint32_t*)&lds[bufi][1][(tid + 256) * 8], 16, 0, 0);       \
    __builtin_amdgcn_global_load_lds(                                          \
        (const __attribute__((address_space(1))) uint32_t*)(B1 + (size_t)(n0 + r0) * K + (kk0) + ks), \
        (__attribute__((address_space(3))) uint32_t*)&lds[bufi][2][tid * 8], 16, 0, 0);               \
    __builtin_amdgcn_global_load_lds(                                          \
        (const __attribute__((address_space(1))) uint32_t*)(B1 + (size_t)(n0 + r1) * K + (kk0) + ks), \
        (__attribute__((address_space(3))) uint32_t*)&lds[bufi][2][(tid + 256) * 8], 16, 0, 0);       \
  } while (0)

  STAGE(0, 0);
  __syncthreads();

  int buf = 0;
  for (int k0 = 0; k0 < K; k0 += BKg) {
    union HU { f16x8 h; u32x4 u; };
    f16x8 af[4], a2f[4], b0f[4], b1f[4];
#pragma unroll
    for (int m = 0; m < 4; ++m) {
      HU t;
      t.h = *(const f16x8*)&lds[buf][0][(wm + m * 16 + fr) * BKg + k8s];
      af[m] = t.h;
      t.u &= 0x10001000u;      // {0,1.0f16} -> {0, 2^-11} exactly
      a2f[m] = t.h;
    }
#pragma unroll
    for (int n = 0; n < 4; ++n) {
      b0f[n] = *(const f16x8*)&lds[buf][1][(wn + n * 16 + fr) * BKg + k8s];
      b1f[n] = *(const f16x8*)&lds[buf][2][(wn + n * 16 + fr) * BKg + k8s];
    }
    if (k0 + BKg < K) STAGE(buf ^ 1, k0 + BKg);
#pragma unroll
    for (int m = 0; m < 4; ++m)
#pragma unroll
      for (int n = 0; n < 4; ++n) {
        acc[m][n] = __builtin_amdgcn_mfma_f32_16x16x32_f16(
            af[m], b0f[n], acc[m][n], 0, 0, 0);
        acc[m][n] = __builtin_amdgcn_mfma_f32_16x16x32_f16(
            a2f[m], b1f[n], acc[m][n], 0, 0, 0);
      }
    __syncthreads();
    buf ^= 1;
  }
#undef STAGE

  const int ccol = lane & 15;
  const int crow = (lane >> 4) * 4;
#pragma unroll
  for (int m = 0; m < 4; ++m)
#pragma unroll
    for (int n = 0; n < 4; ++n)
#pragma unroll
      for (int j = 0; j < 4; ++j) {
        int row = m0 + wm + m * 16 + crow + j;
        int col = n0 + wn + n * 16 + ccol;
        Cout[(size_t)row * N + col] = acc[m][n][j];
      }
}

// ---------------------------------------------------------------------------
// BN2 + LIF2 + residual, chunked T by 8 with next-chunk prefetch.
// Safe when y == out (owner-thread read-before-write per element).
// [VERBATIM round-6 kernel]
// ---------------------------------------------------------------------------
__global__ __launch_bounds__(256) void bn_lif_add(
    const float* __restrict__ y, const ushort* __restrict__ s1b,
    const float* __restrict__ gam, const float* __restrict__ bet,
    const float* __restrict__ mu, const float* __restrict__ var,
    float* __restrict__ out) {
  int gid = blockIdx.x * blockDim.x + threadIdx.x;
  int o = gid & 1023;

  float inv = (float)((double)gam[o] / sqrt((double)var[o] + 1e-5));
  float add = (float)((double)bet[o] - (double)mu[o] * (double)inv);

  float v = 0.f;
  size_t base = (size_t)gid;
  float yv[8]; ushort sv[8];
#pragma unroll
  for (int j = 0; j < 8; ++j) {
    yv[j] = y[base + (size_t)j * BCEL];
    sv[j] = s1b[base + (size_t)j * BCEL];
  }
  for (int c = 0; c < T_ / 8; ++c) {
    int t0 = c * 8;
    float yn[8] = {0,0,0,0,0,0,0,0}; ushort sn[8] = {0,0,0,0,0,0,0,0};
    if (c + 1 < T_ / 8) {
#pragma unroll
      for (int j = 0; j < 8; ++j) {
        size_t idx = base + (size_t)(t0 + 8 + j) * BCEL;
        yn[j] = y[idx];
        sn[j] = s1b[idx];
      }
    }
#pragma unroll
    for (int j = 0; j < 8; ++j) {
      float u = fmaf(yv[j], inv, add);
      v = fmaf(0.5f, v, u);
      bool sp = (v - 1.0f) >= 0.0f;
      float s1v = sv[j] ? 1.0f : 0.0f;
      out[base + (size_t)(t0 + j) * BCEL] = (sp ? 1.0f : 0.0f) + s1v;
      v = sp ? 0.0f : v;
    }
#pragma unroll
    for (int j = 0; j < 8; ++j) { yv[j] = yn[j]; sv[j] = sn[j]; }
  }
}

// ---------------------------------------------------------------------------
extern "C" void kernel_launch(void* const* d_in, const int* in_sizes, int n_in,
                              void* d_out, int out_size, void* d_ws,
                              size_t ws_size, hipStream_t stream) {
  const float* x     = (const float*)d_in[0];
  const float* pw_w  = (const float*)d_in[1];
  const float* pw_b  = (const float*)d_in[2];
  const float* dw_w  = (const float*)d_in[3];
  const float* dw_b  = (const float*)d_in[4];
  const float* bn1g  = (const float*)d_in[5];
  const float* bn1b  = (const float*)d_in[6];
  const float* bn1m  = (const float*)d_in[7];
  const float* bn1v  = (const float*)d_in[8];
  const float* lin_w = (const float*)d_in[9];
  const float* bn2g  = (const float*)d_in[10];
  const float* bn2b  = (const float*)d_in[11];
  const float* bn2m  = (const float*)d_in[12];
  const float* bn2v  = (const float*)d_in[13];

  char* wsb  = (char*)d_ws;
  char* outb = (char*)d_out;
  const size_t PB  = (size_t)M_ * C_ * 4;        // 52,428,800  (p / y, f32)
  const size_t SBB = (size_t)M_ * C_ * 2;        // 26,214,400  (spikes, f16)

  float* p = (float*)d_ws;                       // [B,T,C] f32

  const bool primary = ws_size >= PB + SBB;
  // primary : spikes @ ws+PB, lin-weights @ d_out[0:4MB), y @ ws[0:PB)
  // fallback: spikes @ d_out, memcpy -> ws[0:SBB), weights @ ws+SBB, y @ d_out
  ushort* spikes = primary ? (ushort*)(wsb + PB) : (ushort*)d_out;
  ushort* w0  = primary ? (ushort*)outb : (ushort*)(wsb + SBB);
  ushort* w1s = w0 + (size_t)C_ * C_;
  ushort* Sgemm = primary ? spikes : (ushort*)d_ws;
  float* ybuf = primary ? (float*)d_ws : (float*)d_out;

  // 1) pointwise conv (f32 vector GEMM, exact, fat-tile): p = x.pw_w^T + pw_b
  dim3 pw_grid(M_ / 128, C_ / 128);
  gemm_abt128<<<pw_grid, 256, 0, stream>>>(x, pw_w, pw_b, p, M_, C_, CIN_);

  // 2) depthwise + BN1 + LIF1 -> f16 spike bits [T,B,C]
  dw_bn_lif<<<BCEL / 256, 256, 0, stream>>>(p, dw_w, dw_b, bn1g, bn1b, bn1m,
                                            bn1v, spikes);

  // 3) fallback only: move spikes out of d_out before GEMM overwrites it
  if (!primary)
    hipMemcpyAsync(d_ws, d_out, SBB, hipMemcpyDeviceToDevice, stream);

  // 4) linear weight split
  split_w<<<(C_ * C_ + 255) / 256, 256, 0, stream>>>(lin_w, w0, w1s, C_ * C_);

  // 5) linear MFMA GEMM (r6 pipelined+swizzled): y = S.(w0 + 2^-11 w1s)^T
  gemm_mfma2p<<<(M_ / BM) * (C_ / BN), 256, 0, stream>>>(Sgemm, w0, w1s, ybuf);

  // 6) BN2 + LIF2 + residual -> d_out
  bn_lif_add<<<BCEL / 256, 256, 0, stream>>>(ybuf, Sgemm, bn2g, bn2b, bn2m,
                                             bn2v, (float*)d_out);
}

// Round 10
// 147.386 us; speedup vs baseline: 1.2664x; 1.0433x over previous
//
#include <hip/hip_runtime.h>
#include <hip/hip_bf16.h>
#include <stdint.h>

// Problem constants
#define B_    64
#define T_    200
#define CIN_  80
#define C_    1024
#define M_    (B_ * T_)   // 12800
#define BCEL  (B_ * C_)   // 65536

typedef __attribute__((ext_vector_type(4))) float f32x4;
typedef __attribute__((ext_vector_type(8))) _Float16 f16x8;   // 8 f16 in 4 VGPRs
typedef __attribute__((ext_vector_type(4))) unsigned int u32x4;

// ---------------------------------------------------------------------------
// f32 GEMM (vector ALU) for the pointwise conv. 128x128 tile, 8x8/thread.
// Per-output FMA chain strict ascending-k — bit-identical arithmetic.
// [VERBATIM round-9 kernel]
// ---------------------------------------------------------------------------
__global__ __launch_bounds__(256) void gemm_abt128(
    const float* __restrict__ A, const float* __restrict__ Bm,
    const float* __restrict__ bias, float* __restrict__ C,
    int M, int N, int K) {
  __shared__ float As[16][128];
  __shared__ float Bs[16][128];
  const int tid = threadIdx.x;
  const int tx = tid & 15;
  const int ty = tid >> 4;
  const int m0 = blockIdx.x * 128;
  const int n0 = blockIdx.y * 128;
  const int lr = tid >> 1;
  const int lc = (tid & 1) * 8;

  float acc[8][8] = {};

  const float* Ar = A + (size_t)(m0 + lr) * K + lc;
  const float* Br = Bm + (size_t)(n0 + lr) * K + lc;

  float4 a0 = *(const float4*)(Ar + 0);
  float4 a1 = *(const float4*)(Ar + 4);
  float4 b0 = *(const float4*)(Br + 0);
  float4 b1 = *(const float4*)(Br + 4);

  for (int k0 = 0; k0 < K; k0 += 16) {
    __syncthreads();
    As[lc + 0][lr] = a0.x; As[lc + 1][lr] = a0.y;
    As[lc + 2][lr] = a0.z; As[lc + 3][lr] = a0.w;
    As[lc + 4][lr] = a1.x; As[lc + 5][lr] = a1.y;
    As[lc + 6][lr] = a1.z; As[lc + 7][lr] = a1.w;
    Bs[lc + 0][lr] = b0.x; Bs[lc + 1][lr] = b0.y;
    Bs[lc + 2][lr] = b0.z; Bs[lc + 3][lr] = b0.w;
    Bs[lc + 4][lr] = b1.x; Bs[lc + 5][lr] = b1.y;
    Bs[lc + 6][lr] = b1.z; Bs[lc + 7][lr] = b1.w;
    __syncthreads();
    if (k0 + 16 < K) {
      a0 = *(const float4*)(Ar + k0 + 16);
      a1 = *(const float4*)(Ar + k0 + 20);
      b0 = *(const float4*)(Br + k0 + 16);
      b1 = *(const float4*)(Br + k0 + 20);
    }
#pragma unroll
    for (int kk = 0; kk < 16; ++kk) {
      float4 av0 = *(const float4*)&As[kk][ty * 4];
      float4 av1 = *(const float4*)&As[kk][ty * 4 + 64];
      float4 bv0 = *(const float4*)&Bs[kk][tx * 4];
      float4 bv1 = *(const float4*)&Bs[kk][tx * 4 + 64];
      float avv[8] = {av0.x, av0.y, av0.z, av0.w, av1.x, av1.y, av1.z, av1.w};
      float bvv[8] = {bv0.x, bv0.y, bv0.z, bv0.w, bv1.x, bv1.y, bv1.z, bv1.w};
#pragma unroll
      for (int i = 0; i < 8; ++i)
#pragma unroll
        for (int j = 0; j < 8; ++j)
          acc[i][j] = fmaf(avv[i], bvv[j], acc[i][j]);
    }
  }

  float bj[8] = {0.f, 0.f, 0.f, 0.f, 0.f, 0.f, 0.f, 0.f};
  if (bias) {
#pragma unroll
    for (int j = 0; j < 8; ++j)
      bj[j] = bias[n0 + tx * 4 + (j & 3) + (j >> 2) * 64];
  }
#pragma unroll
  for (int i = 0; i < 8; ++i) {
    int row = m0 + ty * 4 + (i & 3) + (i >> 2) * 64;
    float4 o0, o1;
    o0.x = acc[i][0] + bj[0]; o0.y = acc[i][1] + bj[1];
    o0.z = acc[i][2] + bj[2]; o0.w = acc[i][3] + bj[3];
    o1.x = acc[i][4] + bj[4]; o1.y = acc[i][5] + bj[5];
    o1.z = acc[i][6] + bj[6]; o1.w = acc[i][7] + bj[7];
    *(float4*)&C[(size_t)row * N + n0 + tx * 4] = o0;
    *(float4*)&C[(size_t)row * N + n0 + tx * 4 + 64] = o1;
  }
}

// ---------------------------------------------------------------------------
// Depthwise conv (K=7, same pad) + BN1 + LIF1 scan, chunked T by 8 with
// 8-deep load prefetch. [VERBATIM round-6 kernel]
// ---------------------------------------------------------------------------
__global__ __launch_bounds__(256) void dw_bn_lif(
    const float* __restrict__ p, const float* __restrict__ dw_w,
    const float* __restrict__ dw_b, const float* __restrict__ gam,
    const float* __restrict__ bet, const float* __restrict__ mu,
    const float* __restrict__ var, ushort* __restrict__ s1) {
  int gid = blockIdx.x * blockDim.x + threadIdx.x;
  int b = gid >> 10;
  int o = gid & 1023;

  float w[7];
#pragma unroll
  for (int k = 0; k < 7; ++k) w[k] = dw_w[o * 7 + k];
  float db = dw_b[o];
  float inv = (float)((double)gam[o] / sqrt((double)var[o] + 1e-5));
  float add = (float)((double)bet[o] - (double)mu[o] * (double)inv);

  const float* pp = p + (size_t)b * T_ * C_ + o;
  float win[14];
  win[0] = 0.f; win[1] = 0.f; win[2] = 0.f;
#pragma unroll
  for (int i = 0; i < 11; ++i) win[3 + i] = pp[(size_t)i * C_];

  float v = 0.f;
  size_t obase = (size_t)b * C_ + o;
  for (int c = 0; c < T_ / 8; ++c) {
    int t0 = c * 8;
    float nx[8];
#pragma unroll
    for (int j = 0; j < 8; ++j) {
      int tn = t0 + 11 + j;
      nx[j] = (tn < T_) ? pp[(size_t)tn * C_] : 0.f;
    }
#pragma unroll
    for (int s = 0; s < 8; ++s) {
      float u = db;
#pragma unroll
      for (int k = 0; k < 7; ++k) u = fmaf(w[k], win[s + k], u);
      u = fmaf(u, inv, add);
      v = fmaf(0.5f, v, u);
      bool sp = (v - 1.0f) >= 0.0f;
      s1[obase + (size_t)(t0 + s) * BCEL] = sp ? (ushort)0x3C00 : (ushort)0;
      v = sp ? 0.0f : v;
    }
#pragma unroll
    for (int i = 0; i < 6; ++i) win[i] = win[i + 8];
#pragma unroll
    for (int j = 0; j < 8; ++j) win[6 + j] = nx[j];
  }
}

// ---------------------------------------------------------------------------
// Scaled 2-way f16 split of the linear weights: w ~= w0 + 2^-11 w1s.
// ---------------------------------------------------------------------------
__global__ __launch_bounds__(256) void split_w(
    const float* __restrict__ w, ushort* __restrict__ w0,
    ushort* __restrict__ w1, int n) {
  int i = blockIdx.x * 256 + threadIdx.x;
  if (i >= n) return;
  float x = w[i];
  union { _Float16 h; ushort u; } h0, h1;
  h0.h = (_Float16)x;
  if (fabsf(x) < 6.1035156e-5f) h0.u = 0;
  float r = x - (float)h0.h;
  h1.h = (_Float16)(r * 2048.0f);
  w0[i] = h0.u;
  w1[i] = h1.u;
}

// ---------------------------------------------------------------------------
// MFMA f16 GEMM, 2-term weight split — 8-PHASE 256x256 schedule (T2+T3+T4+T5):
//   y = S*w0^T + (S&0x1000)*w1s^T
// 512 threads (8 waves, 2Mx4N; per-wave C 128x64). K-tile=32, 3 LDS slots
// (144 KB) staged 2 tiles ahead. Phase = {8 ds_read_b128 quadrant frags,
// 2 global_load_lds stage, s_barrier, lgkmcnt(0), setprio(1), 16 MFMA,
// setprio(0), s_barrier}. Counted vmcnt(6) only at phases 4/8 — never drain
// to 0 in the loop. LDS XOR swizzle = r6-proven pair (0 conflicts).
// Per-acc accumulation order identical to r6 (ascending k, base then masked).
// ---------------------------------------------------------------------------
#define GBM 256
#define GBN 256
#define GBK 32
#define NKT (C_ / GBK)   // 32 K-tiles

__global__ __launch_bounds__(512, 2) void gemm_mfma8p(
    const ushort* __restrict__ A,
    const ushort* __restrict__ B0,
    const ushort* __restrict__ B1,
    float* __restrict__ Cout) {
  const int K = C_;
  const int N = C_;
  __shared__ ushort lds8[3][3][GBM * GBK];   // 3 slots x {A,B0,B1} x 16KB = 144KB

  const int tid  = threadIdx.x;
  const int lane = tid & 63;
  const int wid  = tid >> 6;
  const int wm = (wid >> 2) * 128;   // 2 M-groups of waves
  const int wn = (wid & 3) * 64;     // 4 N-groups

  // 200 blocks -> 25 contiguous per XCD (bijective)
  int lin = blockIdx.x;
  int wg  = (lin & 7) * 25 + (lin >> 3);
  const int m0 = (wg >> 2) * GBM;
  const int n0 = (wg & 3) * GBN;

  // staging geometry: 512 thr x 2 x 16B = one 16KB matrix tile; src pre-swizzled
  const int ar0 = tid >> 2, ar1 = ar0 + 128;
  const int aks = ((tid & 3) * 8) ^ (((tid >> 3) & 3) << 3);

  // read-side fragment indices (swizzled column)
  const int fr  = lane & 15;
  const int k8s = ((lane >> 4) * 8) ^ (((fr >> 1) & 3) << 3);

  f32x4 acc[8][4] = {};

#define STG(MATP, RB, MI, SLOT, K0S)                                           \
  do {                                                                         \
    __builtin_amdgcn_global_load_lds(                                          \
        (const __attribute__((address_space(1))) uint32_t*)((MATP) + (size_t)((RB) + ar0) * K + (K0S) + aks), \
        (__attribute__((address_space(3))) uint32_t*)&lds8[SLOT][MI][tid * 8], 16, 0, 0);                     \
    __builtin_amdgcn_global_load_lds(                                          \
        (const __attribute__((address_space(1))) uint32_t*)((MATP) + (size_t)((RB) + ar1) * K + (K0S) + aks), \
        (__attribute__((address_space(3))) uint32_t*)&lds8[SLOT][MI][(tid + 512) * 8], 16, 0, 0);             \
  } while (0)

#define NOSTG ((void)0)
#define VM6 asm volatile("s_waitcnt vmcnt(6)" ::: "memory")

#define PHASE(Q, SRD, STAGE_STMT, VMSTMT)                                      \
  do {                                                                         \
    constexpr int FRB = ((Q) & 1) * 4;                                         \
    constexpr int FCB = ((Q) >> 1) * 2;                                        \
    const ushort* As_  = &lds8[SRD][0][0];                                     \
    const ushort* B0s_ = &lds8[SRD][1][0];                                     \
    const ushort* B1s_ = &lds8[SRD][2][0];                                     \
    f16x8 a0_ = *(const f16x8*)&As_[(wm + (FRB + 0) * 16 + fr) * GBK + k8s];   \
    f16x8 a1_ = *(const f16x8*)&As_[(wm + (FRB + 1) * 16 + fr) * GBK + k8s];   \
    f16x8 a2_ = *(const f16x8*)&As_[(wm + (FRB + 2) * 16 + fr) * GBK + k8s];   \
    f16x8 a3_ = *(const f16x8*)&As_[(wm + (FRB + 3) * 16 + fr) * GBK + k8s];   \
    f16x8 p0_ = *(const f16x8*)&B0s_[(wn + (FCB + 0) * 16 + fr) * GBK + k8s];  \
    f16x8 p1_ = *(const f16x8*)&B0s_[(wn + (FCB + 1) * 16 + fr) * GBK + k8s];  \
    f16x8 q0_ = *(const f16x8*)&B1s_[(wn + (FCB + 0) * 16 + fr) * GBK + k8s];  \
    f16x8 q1_ = *(const f16x8*)&B1s_[(wn + (FCB + 1) * 16 + fr) * GBK + k8s];  \
    STAGE_STMT;                                                                \
    __builtin_amdgcn_s_barrier();                                              \
    asm volatile("s_waitcnt lgkmcnt(0)" ::: "memory");                         \
    __builtin_amdgcn_s_setprio(1);                                             \
    union HU_ { f16x8 h; u32x4 u; };                                           \
    HU_ x0_, x1_, x2_, x3_;                                                    \
    x0_.h = a0_; x0_.u &= 0x10001000u;                                         \
    x1_.h = a1_; x1_.u &= 0x10001000u;                                         \
    x2_.h = a2_; x2_.u &= 0x10001000u;                                         \
    x3_.h = a3_; x3_.u &= 0x10001000u;                                         \
    acc[FRB + 0][FCB + 0] = __builtin_amdgcn_mfma_f32_16x16x32_f16(a0_, p0_, acc[FRB + 0][FCB + 0], 0, 0, 0); \
    acc[FRB + 0][FCB + 0] = __builtin_amdgcn_mfma_f32_16x16x32_f16(x0_.h, q0_, acc[FRB + 0][FCB + 0], 0, 0, 0); \
    acc[FRB + 1][FCB + 0] = __builtin_amdgcn_mfma_f32_16x16x32_f16(a1_, p0_, acc[FRB + 1][FCB + 0], 0, 0, 0); \
    acc[FRB + 1][FCB + 0] = __builtin_amdgcn_mfma_f32_16x16x32_f16(x1_.h, q0_, acc[FRB + 1][FCB + 0], 0, 0, 0); \
    acc[FRB + 2][FCB + 0] = __builtin_amdgcn_mfma_f32_16x16x32_f16(a2_, p0_, acc[FRB + 2][FCB + 0], 0, 0, 0); \
    acc[FRB + 2][FCB + 0] = __builtin_amdgcn_mfma_f32_16x16x32_f16(x2_.h, q0_, acc[FRB + 2][FCB + 0], 0, 0, 0); \
    acc[FRB + 3][FCB + 0] = __builtin_amdgcn_mfma_f32_16x16x32_f16(a3_, p0_, acc[FRB + 3][FCB + 0], 0, 0, 0); \
    acc[FRB + 3][FCB + 0] = __builtin_amdgcn_mfma_f32_16x16x32_f16(x3_.h, q0_, acc[FRB + 3][FCB + 0], 0, 0, 0); \
    acc[FRB + 0][FCB + 1] = __builtin_amdgcn_mfma_f32_16x16x32_f16(a0_, p1_, acc[FRB + 0][FCB + 1], 0, 0, 0); \
    acc[FRB + 0][FCB + 1] = __builtin_amdgcn_mfma_f32_16x16x32_f16(x0_.h, q1_, acc[FRB + 0][FCB + 1], 0, 0, 0); \
    acc[FRB + 1][FCB + 1] = __builtin_amdgcn_mfma_f32_16x16x32_f16(a1_, p1_, acc[FRB + 1][FCB + 1], 0, 0, 0); \
    acc[FRB + 1][FCB + 1] = __builtin_amdgcn_mfma_f32_16x16x32_f16(x1_.h, q1_, acc[FRB + 1][FCB + 1], 0, 0, 0); \
    acc[FRB + 2][FCB + 1] = __builtin_amdgcn_mfma_f32_16x16x32_f16(a2_, p1_, acc[FRB + 2][FCB + 1], 0, 0, 0); \
    acc[FRB + 2][FCB + 1] = __builtin_amdgcn_mfma_f32_16x16x32_f16(x2_.h, q1_, acc[FRB + 2][FCB + 1], 0, 0, 0); \
    acc[FRB + 3][FCB + 1] = __builtin_amdgcn_mfma_f32_16x16x32_f16(a3_, p1_, acc[FRB + 3][FCB + 1], 0, 0, 0); \
    acc[FRB + 3][FCB + 1] = __builtin_amdgcn_mfma_f32_16x16x32_f16(x3_.h, q1_, acc[FRB + 3][FCB + 1], 0, 0, 0); \
    __builtin_amdgcn_s_setprio(0);                                             \
    VMSTMT;                                                                    \
    __builtin_amdgcn_s_barrier();                                              \
  } while (0)

  // prologue: stage t0 -> slot0, t1 -> slot1; wait t0 (allow t1's 6 in flight)
  STG(A, m0, 0, 0, 0);  STG(B0, n0, 1, 0, 0);  STG(B1, n0, 2, 0, 0);
  STG(A, m0, 0, 1, GBK); STG(B0, n0, 1, 1, GBK); STG(B1, n0, 2, 1, GBK);
  asm volatile("s_waitcnt vmcnt(6)" ::: "memory");
  __builtin_amdgcn_s_barrier();

  int s0 = 0;
  for (int it = 0; it < NKT / 2; ++it) {
    const int t0 = 2 * it;
    int s1 = s0 + 1; if (s1 == 3) s1 = 0;
    int s2 = s1 + 1; if (s2 == 3) s2 = 0;           // slot for t0+2 (and read t0+2 later)
    const int ka = (t0 + 2 < NKT) ? (t0 + 2) * GBK : 0;   // clamp: dummy stage
    const int kb = (t0 + 3 < NKT) ? (t0 + 3) * GBK : 0;
    // phases 1-4: consume tile t0 (slot s0); stage t0+2 -> slot s2
    PHASE(0, s0, STG(A,  m0, 0, s2, ka), NOSTG);
    PHASE(1, s0, STG(B0, n0, 1, s2, ka), NOSTG);
    PHASE(2, s0, STG(B1, n0, 2, s2, ka), NOSTG);
    PHASE(3, s0, NOSTG, VM6);
    // phases 5-8: consume tile t1 (slot s1); stage t1+2 -> slot s0
    PHASE(0, s1, STG(A,  m0, 0, s0, kb), NOSTG);
    PHASE(1, s1, STG(B0, n0, 1, s0, kb), NOSTG);
    PHASE(2, s1, STG(B1, n0, 2, s0, kb), NOSTG);
    PHASE(3, s1, NOSTG, VM6);
    s0 = s2;
  }
#undef PHASE
#undef STG

  // epilogue: C/D layout col=lane&15, row=(lane>>4)*4+j
  const int ccol = lane & 15;
  const int crow = (lane >> 4) * 4;
#pragma unroll
  for (int m = 0; m < 8; ++m)
#pragma unroll
    for (int n = 0; n < 4; ++n)
#pragma unroll
      for (int j = 0; j < 4; ++j) {
        int row = m0 + wm + m * 16 + crow + j;
        int col = n0 + wn + n * 16 + ccol;
        Cout[(size_t)row * N + col] = acc[m][n][j];
      }
}

// ---------------------------------------------------------------------------
// BN2 + LIF2 + residual, chunked T by 8 with next-chunk prefetch.
// [VERBATIM round-6 kernel]
// ---------------------------------------------------------------------------
__global__ __launch_bounds__(256) void bn_lif_add(
    const float* __restrict__ y, const ushort* __restrict__ s1b,
    const float* __restrict__ gam, const float* __restrict__ bet,
    const float* __restrict__ mu, const float* __restrict__ var,
    float* __restrict__ out) {
  int gid = blockIdx.x * blockDim.x + threadIdx.x;
  int o = gid & 1023;

  float inv = (float)((double)gam[o] / sqrt((double)var[o] + 1e-5));
  float add = (float)((double)bet[o] - (double)mu[o] * (double)inv);

  float v = 0.f;
  size_t base = (size_t)gid;
  float yv[8]; ushort sv[8];
#pragma unroll
  for (int j = 0; j < 8; ++j) {
    yv[j] = y[base + (size_t)j * BCEL];
    sv[j] = s1b[base + (size_t)j * BCEL];
  }
  for (int c = 0; c < T_ / 8; ++c) {
    int t0 = c * 8;
    float yn[8] = {0,0,0,0,0,0,0,0}; ushort sn[8] = {0,0,0,0,0,0,0,0};
    if (c + 1 < T_ / 8) {
#pragma unroll
      for (int j = 0; j < 8; ++j) {
        size_t idx = base + (size_t)(t0 + 8 + j) * BCEL;
        yn[j] = y[idx];
        sn[j] = s1b[idx];
      }
    }
#pragma unroll
    for (int j = 0; j < 8; ++j) {
      float u = fmaf(yv[j], inv, add);
      v = fmaf(0.5f, v, u);
      bool sp = (v - 1.0f) >= 0.0f;
      float s1v = sv[j] ? 1.0f : 0.0f;
      out[base + (size_t)(t0 + j) * BCEL] = (sp ? 1.0f : 0.0f) + s1v;
      v = sp ? 0.0f : v;
    }
#pragma unroll
    for (int j = 0; j < 8; ++j) { yv[j] = yn[j]; sv[j] = sn[j]; }
  }
}

// ---------------------------------------------------------------------------
extern "C" void kernel_launch(void* const* d_in, const int* in_sizes, int n_in,
                              void* d_out, int out_size, void* d_ws,
                              size_t ws_size, hipStream_t stream) {
  const float* x     = (const float*)d_in[0];
  const float* pw_w  = (const float*)d_in[1];
  const float* pw_b  = (const float*)d_in[2];
  const float* dw_w  = (const float*)d_in[3];
  const float* dw_b  = (const float*)d_in[4];
  const float* bn1g  = (const float*)d_in[5];
  const float* bn1b  = (const float*)d_in[6];
  const float* bn1m  = (const float*)d_in[7];
  const float* bn1v  = (const float*)d_in[8];
  const float* lin_w = (const float*)d_in[9];
  const float* bn2g  = (const float*)d_in[10];
  const float* bn2b  = (const float*)d_in[11];
  const float* bn2m  = (const float*)d_in[12];
  const float* bn2v  = (const float*)d_in[13];

  char* wsb  = (char*)d_ws;
  char* outb = (char*)d_out;
  const size_t PB  = (size_t)M_ * C_ * 4;        // 52,428,800  (p / y, f32)
  const size_t SBB = (size_t)M_ * C_ * 2;        // 26,214,400  (spikes, f16)

  float* p = (float*)d_ws;                       // [B,T,C] f32

  const bool primary = ws_size >= PB + SBB;
  // primary : spikes @ ws+PB, lin-weights @ d_out[0:4MB), y @ ws[0:PB)
  // fallback: spikes @ d_out, memcpy -> ws[0:SBB), weights @ ws+SBB, y @ d_out
  ushort* spikes = primary ? (ushort*)(wsb + PB) : (ushort*)d_out;
  ushort* w0  = primary ? (ushort*)outb : (ushort*)(wsb + SBB);
  ushort* w1s = w0 + (size_t)C_ * C_;
  ushort* Sgemm = primary ? spikes : (ushort*)d_ws;
  float* ybuf = primary ? (float*)d_ws : (float*)d_out;

  // 1) pointwise conv (f32 vector GEMM, exact): p = x . pw_w^T + pw_b
  dim3 pw_grid(M_ / 128, C_ / 128);
  gemm_abt128<<<pw_grid, 256, 0, stream>>>(x, pw_w, pw_b, p, M_, C_, CIN_);

  // 2) depthwise + BN1 + LIF1 -> f16 spike bits [T,B,C]
  dw_bn_lif<<<BCEL / 256, 256, 0, stream>>>(p, dw_w, dw_b, bn1g, bn1b, bn1m,
                                            bn1v, spikes);

  // 3) fallback only: move spikes out of d_out before GEMM overwrites it
  if (!primary)
    hipMemcpyAsync(d_ws, d_out, SBB, hipMemcpyDeviceToDevice, stream);

  // 4) linear weight split
  split_w<<<(C_ * C_ + 255) / 256, 256, 0, stream>>>(lin_w, w0, w1s, C_ * C_);

  // 5) linear MFMA GEMM (8-phase 256^2): y = S.(w0 + 2^-11 w1s)^T
  gemm_mfma8p<<<(M_ / GBM) * (C_ / GBN), 512, 0, stream>>>(Sgemm, w0, w1s,
                                                           ybuf);

  // 6) BN2 + LIF2 + residual -> d_out
  bn_lif_add<<<BCEL / 256, 256, 0, stream>>>(ybuf, Sgemm, bn2g, bn2b, bn2m,
                                             bn2v, (float*)d_out);
}